// Round 1
// 598.791 us; speedup vs baseline: 1.0122x; 1.0122x over previous
//
#include <hip/hip_runtime.h>
#include <hip/hip_fp16.h>
#include <math.h>

// Problem constants: B=8, T=2048, D=1024, K_SIZE=1024, fp32 in/out.
#define B_   8
#define T_   2048
#define D_   1024
#define KSZ  1024
#define NSLOT 16            // T_/128 softmax partial slots (one per row-tile)

typedef _Float16 f16;
typedef _Float16 f16x8 __attribute__((ext_vector_type(8)));
typedef _Float16 f16x4 __attribute__((ext_vector_type(4)));
typedef float f32x4 __attribute__((ext_vector_type(4)));

#define GLOBAL_AS __attribute__((address_space(1)))
#define LDS_AS    __attribute__((address_space(3)))

// Async global->LDS, 16 B per lane. HW: LDS dest = wave-uniform base + lane*16.
static __device__ __forceinline__ void cp16(void* l, const void* g) {
  __builtin_amdgcn_global_load_lds((GLOBAL_AS void*)g, (LDS_AS void*)l, 16, 0, 0);
}

// Guarded online-softmax pair combine: (m1,d1) += (m2,d2)
static __device__ __forceinline__ void sm_combine(float& m1, float& d1,
                                                  float m2, float d2) {
  const float nm = fmaxf(m1, m2);
  float d = 0.f;
  if (d1 > 0.f) d += d1 * __expf(m1 - nm);
  if (d2 > 0.f) d += d2 * __expf(m2 - nm);
  m1 = nm; d1 = d;
}

// ---------------------------------------------------------------------------
// Prep: fp32 -> fp16 cast (vectorized)
// ---------------------------------------------------------------------------
__global__ __launch_bounds__(256)
void cast_f16_kernel(const float* __restrict__ X, f16* __restrict__ Xh) {
  const size_t i = ((size_t)blockIdx.x * 256 + threadIdx.x) * 4;
  float4 v = *(const float4*)&X[i];
  f16x4 o = {(f16)v.x, (f16)v.y, (f16)v.z, (f16)v.w};
  *(f16x4*)&Xh[i] = o;
}

// Prep: W[k][n] -> Wt[n][k] fp16 (1024x1024), LDS-tiled so both the global
// read and the global write are coalesced (old version read stride-4KB).
__global__ __launch_bounds__(256)
void transcast_kernel(const float* __restrict__ W, f16* __restrict__ Wt) {
  __shared__ float tile[32][33];          // +1 pad: conflict-free transpose
  const int c  = threadIdx.x & 31;
  const int r0 = threadIdx.x >> 5;        // 0..7
  const int n0 = blockIdx.x * 32, k0 = blockIdx.y * 32;
#pragma unroll
  for (int rr = 0; rr < 32; rr += 8)
    tile[r0 + rr][c] = W[(size_t)(k0 + r0 + rr) * 1024 + n0 + c];
  __syncthreads();
#pragma unroll
  for (int rr = 0; rr < 32; rr += 8)
    Wt[(size_t)(n0 + r0 + rr) * 1024 + k0 + c] = (f16)tile[c][r0 + rr];
}

// ---------------------------------------------------------------------------
// fp16 MFMA NT-GEMM (projections + PV): C[m,n] = sum_k A[m,k]*B[n,k]
//  EP=0: proj Q/K -> Oh fp16 [16384][1024], +bias
//  EP=1: proj V   -> Vt fp16 [b][v][t] (transposed store), +bias
//  EP=3: PV       -> out fp32 [b][t][v] = acc + Resid; A = P [b][T][T] fp16
//
// K-loop: T3-minimum 2-phase double buffer. Stage tile k+1 into buf^1, then
// counted s_waitcnt vmcnt(4) (tile k's 4 loads done; next tile's stay in
// flight across the barrier), raw s_barrier, ds_read+MFMA on buf, per-wave
// lgkmcnt(0) drain, release barrier. Staging latency overlaps MFMA.
//
// EP=3 load balance: block (jt, pr, b) computes row-tiles it=15-pr AND it=pr
// -> every block runs exactly 17 K-tiles (vs 1..16 before). 512 uniform
// blocks = 2/CU, no idle tail.
// ---------------------------------------------------------------------------
template <int EP>
__global__ __launch_bounds__(256)
void gemm_nt(const f16* __restrict__ A, const f16* __restrict__ Bm,
             const float* __restrict__ bias, f16* __restrict__ Oh,
             float* __restrict__ Of, const float* __restrict__ Resid) {
  constexpr int LDA = (EP == 3) ? T_ : KSZ;
  constexpr int LDB = (EP == 3) ? T_ : KSZ;
  const int jt = blockIdx.x, b = blockIdx.z;
  const int col0 = jt * 128;

  const f16* Ab = A;
  const f16* Bb = Bm;
  if (EP == 3) { Ab += (size_t)b * T_ * T_; Bb += (size_t)b * D_ * T_; }

  __shared__ f16 Ash[2][128 * 32];
  __shared__ f16 Bsh[2][128 * 32];

  const int tid = threadIdx.x;
  const int srow = tid >> 2, sk = (tid & 3) * 8;
  const int lane = tid & 63, wv = tid >> 6;
  const int wm = (wv & 1) * 64, wn = (wv >> 1) * 64;
  const int fr = lane & 15, quad = lane >> 4;

  const f16* bg0 = Bb + (size_t)(col0 + srow) * LDB + sk;
  const f16* bg1 = Bb + (size_t)(col0 + 64 + srow) * LDB + sk;

  for (int part = 0; part < ((EP == 3) ? 2 : 1); ++part) {
    const int it = (EP == 3) ? (part ? (int)blockIdx.y : 15 - (int)blockIdx.y)
                             : (int)blockIdx.y;
    const int kend = (EP == 3) ? (it + 1) * 128 : KSZ;
    const int arow0 = it * 128;
    const f16* ag0 = Ab + (size_t)(arow0 + srow) * LDA + sk;
    const f16* ag1 = Ab + (size_t)(arow0 + 64 + srow) * LDA + sk;

    f32x4 acc[4][4] = {};

    // prologue: stage k=0 into buffer 0
    cp16(&Ash[0][wv * 512], ag0);
    cp16(&Ash[0][2048 + wv * 512], ag1);
    cp16(&Bsh[0][wv * 512], bg0);
    cp16(&Bsh[0][2048 + wv * 512], bg1);
    int cur = 0;
    for (int k0 = 0; k0 < kend; k0 += 32) {
      if (k0 + 32 < kend) {
        const int nb = cur ^ 1;
        cp16(&Ash[nb][wv * 512], ag0 + k0 + 32);
        cp16(&Ash[nb][2048 + wv * 512], ag1 + k0 + 32);
        cp16(&Bsh[nb][wv * 512], bg0 + k0 + 32);
        cp16(&Bsh[nb][2048 + wv * 512], bg1 + k0 + 32);
        asm volatile("s_waitcnt vmcnt(4)" ::: "memory");
      } else {
        asm volatile("s_waitcnt vmcnt(0)" ::: "memory");
      }
      __builtin_amdgcn_s_barrier();      // current tile visible to all waves
      asm volatile("" ::: "memory");
      f16x8 af[4], bf[4];
#pragma unroll
      for (int mi = 0; mi < 4; ++mi)
        af[mi] = *(const f16x8*)&Ash[cur][(wm + mi * 16 + fr) * 32 + quad * 8];
#pragma unroll
      for (int ni = 0; ni < 4; ++ni)
        bf[ni] = *(const f16x8*)&Bsh[cur][(wn + ni * 16 + fr) * 32 + quad * 8];
#pragma unroll
      for (int mi = 0; mi < 4; ++mi)
#pragma unroll
        for (int ni = 0; ni < 4; ++ni)
          acc[mi][ni] = __builtin_amdgcn_mfma_f32_16x16x32_f16(af[mi], bf[ni], acc[mi][ni], 0, 0, 0);
      // per-wave: all ds_reads of buf[cur] complete before release barrier
      asm volatile("s_waitcnt lgkmcnt(0)" ::: "memory");
      __builtin_amdgcn_s_barrier();      // buf[cur] may now be overwritten
      asm volatile("" ::: "memory");
      cur ^= 1;
    }

#pragma unroll
    for (int mi = 0; mi < 4; ++mi) {
#pragma unroll
      for (int ni = 0; ni < 4; ++ni) {
        const int col = col0 + wn + ni * 16 + fr;
        float bc = 0.f;
        if (EP == 0 || EP == 1) bc = bias[col];
        const int r0 = wm + mi * 16 + quad * 4;
        f32x4 v = acc[mi][ni];
        if (EP == 0) {
          const int grow = it * 128 + r0;
#pragma unroll
          for (int rg = 0; rg < 4; ++rg)
            Oh[(size_t)(grow + rg) * KSZ + col] = (f16)(v[rg] + bc);
        } else if (EP == 1) {
          const int grow = it * 128 + r0;
          const int bb = grow >> 11, t0 = grow & 2047;
          f16x4 pk;
#pragma unroll
          for (int rg = 0; rg < 4; ++rg) pk[rg] = (f16)(v[rg] + bc);
          *(f16x4*)&Oh[((size_t)bb * D_ + col) * T_ + t0] = pk;
        } else {
          const int grow = it * 128 + r0;
#pragma unroll
          for (int rg = 0; rg < 4; ++rg) {
            const size_t o = ((size_t)b * T_ + grow + rg) * D_ + col;
            Of[o] = v[rg] + Resid[o];
          }
        }
      }
    }
  }
}

// ---------------------------------------------------------------------------
// Triangular QK kernel. S[i,j] = Q_i . K_j for tiles jt <= it.
//  STATS=1 (pass A): per-column (m, sum-exp) over the block's 128 rows ->
//                    pm/pd[it][b][j]. No S storage.
//  STATS=0 (pass B): P[i,j] = exp(S - mcol_j)*rcol_j (0 for j>i) -> Pc fp16.
// Same 2-phase double-buffered K-loop as gemm_nt.
// ---------------------------------------------------------------------------
template <int STATS>
__global__ __launch_bounds__(256)
void qk_tri(const f16* __restrict__ Q, const f16* __restrict__ Km,
            float* __restrict__ pm, float* __restrict__ pd,
            const float* __restrict__ mcol, const float* __restrict__ rcol,
            f16* __restrict__ Pc) {
  const int jt = blockIdx.x, itg = blockIdx.y, b = blockIdx.z;
  if (jt > itg) return;
  const bool diag = (jt == itg);

  const f16* Ab = Q  + (size_t)b * T_ * KSZ;
  const f16* Bb = Km + (size_t)b * T_ * KSZ;
  const int arow0 = itg * 128, col0 = jt * 128;

  __shared__ f16 Ash[2][128 * 32];
  __shared__ f16 Bsh[2][128 * 32];
  __shared__ float red_m[4][64];
  __shared__ float red_d[4][64];

  const int tid = threadIdx.x;
  const int srow = tid >> 2, sk = (tid & 3) * 8;
  const f16* ag0 = Ab + (size_t)(arow0 + srow) * KSZ + sk;
  const f16* ag1 = Ab + (size_t)(arow0 + 64 + srow) * KSZ + sk;
  const f16* bg0 = Bb + (size_t)(col0 + srow) * KSZ + sk;
  const f16* bg1 = Bb + (size_t)(col0 + 64 + srow) * KSZ + sk;

  const int lane = tid & 63, wv = tid >> 6;
  const int wm = (wv & 1) * 64, wn = (wv >> 1) * 64;
  const int fr = lane & 15, quad = lane >> 4;

  f32x4 acc[4][4] = {};

  // prologue: stage k=0 into buffer 0
  cp16(&Ash[0][wv * 512], ag0);
  cp16(&Ash[0][2048 + wv * 512], ag1);
  cp16(&Bsh[0][wv * 512], bg0);
  cp16(&Bsh[0][2048 + wv * 512], bg1);
  int cur = 0;
  for (int k0 = 0; k0 < KSZ; k0 += 32) {
    if (k0 + 32 < KSZ) {
      const int nb = cur ^ 1;
      cp16(&Ash[nb][wv * 512], ag0 + k0 + 32);
      cp16(&Ash[nb][2048 + wv * 512], ag1 + k0 + 32);
      cp16(&Bsh[nb][wv * 512], bg0 + k0 + 32);
      cp16(&Bsh[nb][2048 + wv * 512], bg1 + k0 + 32);
      asm volatile("s_waitcnt vmcnt(4)" ::: "memory");
    } else {
      asm volatile("s_waitcnt vmcnt(0)" ::: "memory");
    }
    __builtin_amdgcn_s_barrier();
    asm volatile("" ::: "memory");
    f16x8 af[4], bf[4];
#pragma unroll
    for (int mi = 0; mi < 4; ++mi)
      af[mi] = *(const f16x8*)&Ash[cur][(wm + mi * 16 + fr) * 32 + quad * 8];
#pragma unroll
    for (int ni = 0; ni < 4; ++ni)
      bf[ni] = *(const f16x8*)&Bsh[cur][(wn + ni * 16 + fr) * 32 + quad * 8];
#pragma unroll
    for (int mi = 0; mi < 4; ++mi)
#pragma unroll
      for (int ni = 0; ni < 4; ++ni)
        acc[mi][ni] = __builtin_amdgcn_mfma_f32_16x16x32_f16(af[mi], bf[ni], acc[mi][ni], 0, 0, 0);
    asm volatile("s_waitcnt lgkmcnt(0)" ::: "memory");
    __builtin_amdgcn_s_barrier();
    asm volatile("" ::: "memory");
    cur ^= 1;
  }

  if (STATS) {
    // Per-column (m, d) over this block's 128 rows. Two-pass: max, then exp.
#pragma unroll
    for (int ni = 0; ni < 4; ++ni) {
      const int gj = col0 + wn + ni * 16 + fr;
      float lm = -INFINITY;
#pragma unroll
      for (int mi = 0; mi < 4; ++mi) {
        const int gi0 = arow0 + wm + mi * 16 + quad * 4;
#pragma unroll
        for (int rg = 0; rg < 4; ++rg)
          if (!diag || (gi0 + rg >= gj)) lm = fmaxf(lm, acc[mi][ni][rg]);
      }
      float ld = 0.f;
#pragma unroll
      for (int mi = 0; mi < 4; ++mi) {
        const int gi0 = arow0 + wm + mi * 16 + quad * 4;
#pragma unroll
        for (int rg = 0; rg < 4; ++rg)
          if (!diag || (gi0 + rg >= gj)) ld += __expf(acc[mi][ni][rg] - lm);
      }
      // Butterfly across the 4 quads (lanes fr, fr+16, fr+32, fr+48).
      sm_combine(lm, ld, __shfl_xor(lm, 16), __shfl_xor(ld, 16));
      sm_combine(lm, ld, __shfl_xor(lm, 32), __shfl_xor(ld, 32));
      if (quad == 0) { red_m[wv][ni * 16 + fr] = lm; red_d[wv][ni * 16 + fr] = ld; }
    }
    __syncthreads();
    if (tid < 128) {
      const int c = tid;                     // block-local column 0..127
      const int w0 = (c < 64) ? 0 : 2;       // waves (w0, w0+1) cover col c
      const int cc = c & 63;
      float m1 = red_m[w0][cc], d1 = red_d[w0][cc];
      sm_combine(m1, d1, red_m[w0 + 1][cc], red_d[w0 + 1][cc]);
      const int idx = (itg * B_ + b) * T_ + col0 + c;
      pm[idx] = m1;
      pd[idx] = d1;
    }
  } else {
    // P = exp(S - m_j) * r_j for j<=i, 0 above diagonal; fp16 store.
    f16* Pb = Pc + (size_t)b * T_ * T_;
    const float* mc = mcol + b * T_;
    const float* rc = rcol + b * T_;
#pragma unroll
    for (int ni = 0; ni < 4; ++ni) {
      const int gj = col0 + wn + ni * 16 + fr;
      const float mj = mc[gj], rj = rc[gj];
#pragma unroll
      for (int mi = 0; mi < 4; ++mi) {
        const int gi0 = arow0 + wm + mi * 16 + quad * 4;
#pragma unroll
        for (int rg = 0; rg < 4; ++rg) {
          float v = 0.f;
          if (!diag || (gi0 + rg >= gj))
            v = __expf(acc[mi][ni][rg] - mj) * rj;
          Pb[(size_t)(gi0 + rg) * T_ + gj] = (f16)v;
        }
      }
    }
  }
}

// ---------------------------------------------------------------------------
// Combine NSLOT partials per column; fold 1/sqrt(K)=1/32 into rcol.
// ---------------------------------------------------------------------------
__global__ __launch_bounds__(256)
void colstats_combine(const float* __restrict__ pm, const float* __restrict__ pd,
                      float* __restrict__ mcol, float* __restrict__ rcol) {
  const int j = blockIdx.x * 256 + threadIdx.x;
  const int b = blockIdx.y;
  float m = -INFINITY, d = 0.f;
  for (int s = 0; s < NSLOT; ++s) {
    const int idx = (s * B_ + b) * T_ + j;
    const float pmv = pm[idx], pdv = pd[idx];
    if (pdv > 0.f) sm_combine(m, d, pmv, pdv);
  }
  mcol[b * T_ + j] = m;
  rcol[b * T_ + j] = 1.f / (d * 32.f);
}

// ---------------------------------------------------------------------------
extern "C" void kernel_launch(void* const* d_in, const int* in_sizes, int n_in,
                              void* d_out, int out_size, void* d_ws, size_t ws_size,
                              hipStream_t stream) {
  const float* X  = (const float*)d_in[0];
  const float* Wq = (const float*)d_in[1];
  const float* bq = (const float*)d_in[2];
  const float* Wk = (const float*)d_in[3];
  const float* bk = (const float*)d_in[4];
  const float* Wv = (const float*)d_in[5];
  const float* bv = (const float*)d_in[6];
  float* out = (float*)d_out;

  // Workspace carve (~210 MB)
  char* p = (char*)d_ws;
  auto carve = [&](size_t bytes) { char* r = p; p += (bytes + 255) & ~(size_t)255; return r; };
  f16*   Xh   = (f16*)carve((size_t)B_ * T_ * D_ * 2);
  f16*   Wqt  = (f16*)carve((size_t)D_ * KSZ * 2);
  f16*   Wkt  = (f16*)carve((size_t)D_ * KSZ * 2);
  f16*   Wvt  = (f16*)carve((size_t)D_ * D_ * 2);
  f16*   Qh   = (f16*)carve((size_t)B_ * T_ * KSZ * 2);
  f16*   Kh   = (f16*)carve((size_t)B_ * T_ * KSZ * 2);
  f16*   Vt   = (f16*)carve((size_t)B_ * D_ * T_ * 2);
  f16*   Pc   = (f16*)carve((size_t)B_ * T_ * T_ * 2);
  float* pm   = (float*)carve((size_t)NSLOT * B_ * T_ * 4);
  float* pd   = (float*)carve((size_t)NSLOT * B_ * T_ * 4);
  float* mcol = (float*)carve((size_t)B_ * T_ * 4);
  float* rcol = (float*)carve((size_t)B_ * T_ * 4);

  const dim3 blk(256);

  // Prep: casts + weight transposes; zero pd (skipped tiles never write it).
  hipMemsetAsync(pd, 0, (size_t)NSLOT * B_ * T_ * 4, stream);
  cast_f16_kernel<<<dim3((B_ * T_ * D_ / 4) / 256), blk, 0, stream>>>(X, Xh);
  transcast_kernel<<<dim3(32, 32), blk, 0, stream>>>(Wq, Wqt);
  transcast_kernel<<<dim3(32, 32), blk, 0, stream>>>(Wk, Wkt);
  transcast_kernel<<<dim3(32, 32), blk, 0, stream>>>(Wv, Wvt);

  // Projections (MFMA)
  gemm_nt<0><<<dim3(KSZ / 128, (B_ * T_) / 128, 1), blk, 0, stream>>>(Xh, Wqt, bq, Qh, nullptr, nullptr);
  gemm_nt<0><<<dim3(KSZ / 128, (B_ * T_) / 128, 1), blk, 0, stream>>>(Xh, Wkt, bk, Kh, nullptr, nullptr);
  gemm_nt<1><<<dim3(D_ / 128, (B_ * T_) / 128, 1), blk, 0, stream>>>(Xh, Wvt, bv, Vt, nullptr, nullptr);

  // Pass A: fused QK + per-tile column softmax stats (no S storage)
  qk_tri<1><<<dim3(T_ / 128, T_ / 128, B_), blk, 0, stream>>>(Qh, Kh, pm, pd, nullptr, nullptr, nullptr);
  colstats_combine<<<dim3(T_ / 256, B_), blk, 0, stream>>>(pm, pd, mcol, rcol);

  // Pass B: fused QK + normalize -> fp16 P (full triangle)
  qk_tri<0><<<dim3(T_ / 128, T_ / 128, B_), blk, 0, stream>>>(Qh, Kh, nullptr, nullptr, mcol, rcol, Pc);

  // PV + residual: paired row-tiles (pr, 15-pr) -> uniform 17 K-tiles/block
  gemm_nt<3><<<dim3(D_ / 128, T_ / 256, B_), blk, 0, stream>>>(Pc, Vt, nullptr, nullptr, out, X);
}

// Round 2
// 489.491 us; speedup vs baseline: 1.2382x; 1.2233x over previous
//
#include <hip/hip_runtime.h>
#include <hip/hip_fp16.h>
#include <math.h>

// Problem constants: B=8, T=2048, D=1024, K_SIZE=1024, fp32 in/out.
#define B_   8
#define T_   2048
#define D_   1024
#define KSZ  1024
#define NSLOT 16            // T_/128 softmax partial slots (one per row-tile)
#define NTRI  136           // 16*17/2 lower-triangle 128x128 tiles

typedef _Float16 f16;
typedef _Float16 f16x8 __attribute__((ext_vector_type(8)));
typedef _Float16 f16x4 __attribute__((ext_vector_type(4)));
typedef float f32x4 __attribute__((ext_vector_type(4)));

#define GLOBAL_AS __attribute__((address_space(1)))
#define LDS_AS    __attribute__((address_space(3)))

// Async global->LDS, 16 B per lane. HW: LDS dest = wave-uniform base + lane*16.
static __device__ __forceinline__ void cp16(void* l, const void* g) {
  __builtin_amdgcn_global_load_lds((GLOBAL_AS void*)g, (LDS_AS void*)l, 16, 0, 0);
}

// Guarded online-softmax pair combine: (m1,d1) += (m2,d2)
static __device__ __forceinline__ void sm_combine(float& m1, float& d1,
                                                  float m2, float d2) {
  const float nm = fmaxf(m1, m2);
  float d = 0.f;
  if (d1 > 0.f) d += d1 * __expf(m1 - nm);
  if (d2 > 0.f) d += d2 * __expf(m2 - nm);
  m1 = nm; d1 = d;
}

// ---------------------------------------------------------------------------
// Prep: fp32 -> fp16 cast (vectorized)
// ---------------------------------------------------------------------------
__global__ __launch_bounds__(256)
void cast_f16_kernel(const float* __restrict__ X, f16* __restrict__ Xh) {
  const size_t i = ((size_t)blockIdx.x * 256 + threadIdx.x) * 4;
  float4 v = *(const float4*)&X[i];
  f16x4 o = {(f16)v.x, (f16)v.y, (f16)v.z, (f16)v.w};
  *(f16x4*)&Xh[i] = o;
}

// Prep: W[k][n] -> Wt[n][k] fp16 (1024x1024), LDS-tiled (coalesced both sides)
__global__ __launch_bounds__(256)
void transcast_kernel(const float* __restrict__ W, f16* __restrict__ Wt) {
  __shared__ float tile[32][33];          // +1 pad: conflict-free transpose
  const int c  = threadIdx.x & 31;
  const int r0 = threadIdx.x >> 5;        // 0..7
  const int n0 = blockIdx.x * 32, k0 = blockIdx.y * 32;
#pragma unroll
  for (int rr = 0; rr < 32; rr += 8)
    tile[r0 + rr][c] = W[(size_t)(k0 + r0 + rr) * 1024 + n0 + c];
  __syncthreads();
#pragma unroll
  for (int rr = 0; rr < 32; rr += 8)
    Wt[(size_t)(n0 + r0 + rr) * 1024 + k0 + c] = (f16)tile[c][r0 + rr];
}

// ---------------------------------------------------------------------------
// fp16 MFMA NT-GEMM (projections + PV): C[m,n] = sum_k A[m,k]*B[n,k]
//  EP=0: proj Q/K -> Oh fp16 [16384][1024], +bias
//  EP=1: proj V   -> Vt fp16 [b][v][t] (transposed store), +bias
//  EP=3: PV       -> out fp32 [b][t][v] = acc + Resid; A = P [b][T][T] fp16
//
// K-loop: depth-2 pipeline, 3 LDS buffers. Two tiles always in flight
// (counted s_waitcnt vmcnt(8) in steady state; peeled vmcnt(4)/vmcnt(0)
// tail) -> ~2 K-steps of MFMA time cover the HBM/L2 load latency, which a
// depth-1 double buffer (~260 cyc) could not. Raw s_barrier; per-wave
// lgkmcnt(0) drain before the release barrier.
//
// EP=3 load balance: block (jt, pr, b) computes row-tiles it=15-pr AND it=pr
// -> every block runs exactly 17 K-tiles. 512 uniform blocks.
// ---------------------------------------------------------------------------
template <int EP>
__global__ __launch_bounds__(256)
void gemm_nt(const f16* __restrict__ A, const f16* __restrict__ Bm,
             const float* __restrict__ bias, f16* __restrict__ Oh,
             float* __restrict__ Of, const float* __restrict__ Resid) {
  constexpr int LDA = (EP == 3) ? T_ : KSZ;
  constexpr int LDB = (EP == 3) ? T_ : KSZ;
  const int jt = blockIdx.x, b = blockIdx.z;
  const int col0 = jt * 128;

  const f16* Ab = A;
  const f16* Bb = Bm;
  if (EP == 3) { Ab += (size_t)b * T_ * T_; Bb += (size_t)b * D_ * T_; }

  __shared__ f16 Ash[3][128 * 32];
  __shared__ f16 Bsh[3][128 * 32];

  const int tid = threadIdx.x;
  const int srow = tid >> 2, sk = (tid & 3) * 8;
  const int lane = tid & 63, wv = tid >> 6;
  const int wm = (wv & 1) * 64, wn = (wv >> 1) * 64;
  const int fr = lane & 15, quad = lane >> 4;

  const f16* bg0 = Bb + (size_t)(col0 + srow) * LDB + sk;
  const f16* bg1 = Bb + (size_t)(col0 + 64 + srow) * LDB + sk;

  for (int part = 0; part < ((EP == 3) ? 2 : 1); ++part) {
    const int it = (EP == 3) ? (part ? (int)blockIdx.y : 15 - (int)blockIdx.y)
                             : (int)blockIdx.y;
    const int kend = (EP == 3) ? (it + 1) * 128 : KSZ;
    const int nt = kend >> 5;              // K-steps of 32; nt >= 4 always
    const int arow0 = it * 128;
    const f16* ag0 = Ab + (size_t)(arow0 + srow) * LDA + sk;
    const f16* ag1 = Ab + (size_t)(arow0 + 64 + srow) * LDA + sk;

    f32x4 acc[4][4] = {};

    // prologue: stage tiles 0 and 1
#pragma unroll
    for (int pt = 0; pt < 2; ++pt) {
      cp16(&Ash[pt][wv * 512], ag0 + pt * 32);
      cp16(&Ash[pt][2048 + wv * 512], ag1 + pt * 32);
      cp16(&Bsh[pt][wv * 512], bg0 + pt * 32);
      cp16(&Bsh[pt][2048 + wv * 512], bg1 + pt * 32);
    }
    int cur = 0;
    for (int t = 0; t < nt; ++t) {
      const int ahead = nt - 1 - t;
      if (ahead >= 2) {
        int pb = cur + 2; if (pb >= 3) pb -= 3;
        const int ko = (t + 2) * 32;
        cp16(&Ash[pb][wv * 512], ag0 + ko);
        cp16(&Ash[pb][2048 + wv * 512], ag1 + ko);
        cp16(&Bsh[pb][wv * 512], bg0 + ko);
        cp16(&Bsh[pb][2048 + wv * 512], bg1 + ko);
        asm volatile("s_waitcnt vmcnt(8)" ::: "memory");
      } else if (ahead == 1) {
        asm volatile("s_waitcnt vmcnt(4)" ::: "memory");
      } else {
        asm volatile("s_waitcnt vmcnt(0)" ::: "memory");
      }
      __builtin_amdgcn_s_barrier();      // tile t visible to all waves
      asm volatile("" ::: "memory");
      f16x8 af[4], bf[4];
#pragma unroll
      for (int mi = 0; mi < 4; ++mi)
        af[mi] = *(const f16x8*)&Ash[cur][(wm + mi * 16 + fr) * 32 + quad * 8];
#pragma unroll
      for (int ni = 0; ni < 4; ++ni)
        bf[ni] = *(const f16x8*)&Bsh[cur][(wn + ni * 16 + fr) * 32 + quad * 8];
#pragma unroll
      for (int mi = 0; mi < 4; ++mi)
#pragma unroll
        for (int ni = 0; ni < 4; ++ni)
          acc[mi][ni] = __builtin_amdgcn_mfma_f32_16x16x32_f16(af[mi], bf[ni], acc[mi][ni], 0, 0, 0);
      // per-wave: all ds_reads of buf[cur] complete before release barrier
      asm volatile("s_waitcnt lgkmcnt(0)" ::: "memory");
      __builtin_amdgcn_s_barrier();      // buf[cur] may now be overwritten
      asm volatile("" ::: "memory");
      cur = (cur == 2) ? 0 : cur + 1;
    }

#pragma unroll
    for (int mi = 0; mi < 4; ++mi) {
#pragma unroll
      for (int ni = 0; ni < 4; ++ni) {
        const int col = col0 + wn + ni * 16 + fr;
        float bc = 0.f;
        if (EP == 0 || EP == 1) bc = bias[col];
        const int r0 = wm + mi * 16 + quad * 4;
        f32x4 v = acc[mi][ni];
        if (EP == 0) {
          const int grow = it * 128 + r0;
#pragma unroll
          for (int rg = 0; rg < 4; ++rg)
            Oh[(size_t)(grow + rg) * KSZ + col] = (f16)(v[rg] + bc);
        } else if (EP == 1) {
          const int grow = it * 128 + r0;
          const int bb = grow >> 11, t0 = grow & 2047;
          f16x4 pk;
#pragma unroll
          for (int rg = 0; rg < 4; ++rg) pk[rg] = (f16)(v[rg] + bc);
          *(f16x4*)&Oh[((size_t)bb * D_ + col) * T_ + t0] = pk;
        } else {
          const int grow = it * 128 + r0;
#pragma unroll
          for (int rg = 0; rg < 4; ++rg) {
            const size_t o = ((size_t)b * T_ + grow + rg) * D_ + col;
            Of[o] = v[rg] + Resid[o];
          }
        }
      }
    }
  }
}

// ---------------------------------------------------------------------------
// Fused triangular QK pass: S[i,j] = Q_i . K_j for lower-triangle tiles.
// Computes per-tile column stats (m, sum-exp) -> pm/pd AND stores
// E = exp(S - m_tile_j) (in [0,1], fp16-exact to 2^-11) into Ec.
// Pass B's full QK recompute is thereby eliminated: the later pnorm kernel
// rescales E elementwise by exp(m_tile - m_col) * r_col.
// Grid: (NTRI, B_) — only real tiles launched.
// ---------------------------------------------------------------------------
__global__ __launch_bounds__(256)
void qk_fused(const f16* __restrict__ Q, const f16* __restrict__ Km,
              float* __restrict__ pm, float* __restrict__ pd,
              f16* __restrict__ Ec) {
  const int p = blockIdx.x, b = blockIdx.y;
  int itg = (int)((sqrtf(8.f * p + 1.f) - 1.f) * 0.5f);
  while ((itg + 1) * (itg + 2) / 2 <= p) ++itg;
  while (itg * (itg + 1) / 2 > p) --itg;
  const int jt = p - itg * (itg + 1) / 2;
  const bool diag = (jt == itg);

  const f16* Ab = Q  + (size_t)b * T_ * KSZ;
  const f16* Bb = Km + (size_t)b * T_ * KSZ;
  const int arow0 = itg * 128, col0 = jt * 128;

  __shared__ f16 Ash[3][128 * 32];
  __shared__ f16 Bsh[3][128 * 32];
  __shared__ float red_m[4][64];
  __shared__ float red_d[4][64];
  __shared__ float mb[128];

  const int tid = threadIdx.x;
  const int srow = tid >> 2, sk = (tid & 3) * 8;
  const f16* ag0 = Ab + (size_t)(arow0 + srow) * KSZ + sk;
  const f16* ag1 = Ab + (size_t)(arow0 + 64 + srow) * KSZ + sk;
  const f16* bg0 = Bb + (size_t)(col0 + srow) * KSZ + sk;
  const f16* bg1 = Bb + (size_t)(col0 + 64 + srow) * KSZ + sk;

  const int lane = tid & 63, wv = tid >> 6;
  const int wm = (wv & 1) * 64, wn = (wv >> 1) * 64;
  const int fr = lane & 15, quad = lane >> 4;

  f32x4 acc[4][4] = {};

  constexpr int nt = KSZ / 32;
  // prologue: stage tiles 0 and 1
#pragma unroll
  for (int pt = 0; pt < 2; ++pt) {
    cp16(&Ash[pt][wv * 512], ag0 + pt * 32);
    cp16(&Ash[pt][2048 + wv * 512], ag1 + pt * 32);
    cp16(&Bsh[pt][wv * 512], bg0 + pt * 32);
    cp16(&Bsh[pt][2048 + wv * 512], bg1 + pt * 32);
  }
  int cur = 0;
  for (int t = 0; t < nt; ++t) {
    const int ahead = nt - 1 - t;
    if (ahead >= 2) {
      int pb = cur + 2; if (pb >= 3) pb -= 3;
      const int ko = (t + 2) * 32;
      cp16(&Ash[pb][wv * 512], ag0 + ko);
      cp16(&Ash[pb][2048 + wv * 512], ag1 + ko);
      cp16(&Bsh[pb][wv * 512], bg0 + ko);
      cp16(&Bsh[pb][2048 + wv * 512], bg1 + ko);
      asm volatile("s_waitcnt vmcnt(8)" ::: "memory");
    } else if (ahead == 1) {
      asm volatile("s_waitcnt vmcnt(4)" ::: "memory");
    } else {
      asm volatile("s_waitcnt vmcnt(0)" ::: "memory");
    }
    __builtin_amdgcn_s_barrier();
    asm volatile("" ::: "memory");
    f16x8 af[4], bf[4];
#pragma unroll
    for (int mi = 0; mi < 4; ++mi)
      af[mi] = *(const f16x8*)&Ash[cur][(wm + mi * 16 + fr) * 32 + quad * 8];
#pragma unroll
    for (int ni = 0; ni < 4; ++ni)
      bf[ni] = *(const f16x8*)&Bsh[cur][(wn + ni * 16 + fr) * 32 + quad * 8];
#pragma unroll
    for (int mi = 0; mi < 4; ++mi)
#pragma unroll
      for (int ni = 0; ni < 4; ++ni)
        acc[mi][ni] = __builtin_amdgcn_mfma_f32_16x16x32_f16(af[mi], bf[ni], acc[mi][ni], 0, 0, 0);
    asm volatile("s_waitcnt lgkmcnt(0)" ::: "memory");
    __builtin_amdgcn_s_barrier();
    asm volatile("" ::: "memory");
    cur = (cur == 2) ? 0 : cur + 1;
  }

  // --- per-column (m, d) over this block's 128 rows: two-pass max then exp.
#pragma unroll
  for (int ni = 0; ni < 4; ++ni) {
    const int gj = col0 + wn + ni * 16 + fr;
    float lm = -INFINITY;
#pragma unroll
    for (int mi = 0; mi < 4; ++mi) {
      const int gi0 = arow0 + wm + mi * 16 + quad * 4;
#pragma unroll
      for (int rg = 0; rg < 4; ++rg)
        if (!diag || (gi0 + rg >= gj)) lm = fmaxf(lm, acc[mi][ni][rg]);
    }
    float ld = 0.f;
#pragma unroll
    for (int mi = 0; mi < 4; ++mi) {
      const int gi0 = arow0 + wm + mi * 16 + quad * 4;
#pragma unroll
      for (int rg = 0; rg < 4; ++rg)
        if (!diag || (gi0 + rg >= gj)) ld += __expf(acc[mi][ni][rg] - lm);
    }
    // Butterfly across the 4 quads (lanes fr, fr+16, fr+32, fr+48).
    sm_combine(lm, ld, __shfl_xor(lm, 16), __shfl_xor(ld, 16));
    sm_combine(lm, ld, __shfl_xor(lm, 32), __shfl_xor(ld, 32));
    if (quad == 0) { red_m[wv][ni * 16 + fr] = lm; red_d[wv][ni * 16 + fr] = ld; }
  }
  __syncthreads();
  if (tid < 128) {
    const int c = tid;                     // block-local column 0..127
    const int w0 = (c < 64) ? 0 : 2;       // waves (w0, w0+1) cover col c
    const int cc = c & 63;
    float m1 = red_m[w0][cc], d1 = red_d[w0][cc];
    sm_combine(m1, d1, red_m[w0 + 1][cc], red_d[w0 + 1][cc]);
    const int idx = (itg * B_ + b) * T_ + col0 + c;
    pm[idx] = m1;
    pd[idx] = d1;
    mb[c] = m1;                            // broadcast block-column max
  }
  __syncthreads();

  // --- store E = exp(S - m_tile_j) fp16 (0 above the diagonal).
  f16* Eb = Ec + (size_t)b * T_ * T_;
#pragma unroll
  for (int ni = 0; ni < 4; ++ni) {
    const int cl = wn + ni * 16 + fr;      // block-local column
    const int gj = col0 + cl;
    const float mj = mb[cl];
#pragma unroll
    for (int mi = 0; mi < 4; ++mi) {
      const int gi0 = arow0 + wm + mi * 16 + quad * 4;
#pragma unroll
      for (int rg = 0; rg < 4; ++rg) {
        float v = 0.f;
        if (!diag || (gi0 + rg >= gj)) v = __expf(acc[mi][ni][rg] - mj);
        Eb[(size_t)(gi0 + rg) * T_ + gj] = (f16)v;
      }
    }
  }
}

// ---------------------------------------------------------------------------
// Combine NSLOT partials per column; fold 1/sqrt(K)=1/32 into rcol.
// ---------------------------------------------------------------------------
__global__ __launch_bounds__(256)
void colstats_combine(const float* __restrict__ pm, const float* __restrict__ pd,
                      float* __restrict__ mcol, float* __restrict__ rcol) {
  const int j = blockIdx.x * 256 + threadIdx.x;
  const int b = blockIdx.y;
  float m = -INFINITY, d = 0.f;
  for (int s = 0; s < NSLOT; ++s) {
    const int idx = (s * B_ + b) * T_ + j;
    const float pmv = pm[idx], pdv = pd[idx];
    if (pdv > 0.f) sm_combine(m, d, pmv, pdv);
  }
  mcol[b * T_ + j] = m;
  rcol[b * T_ + j] = 1.f / (d * 32.f);
}

// ---------------------------------------------------------------------------
// Elementwise normalize (in place): P = E * exp(pm_tile - m_col) * r_col.
// One block per lower-triangle tile; 70 MB RMW total (~15 us, BW-bound).
// ---------------------------------------------------------------------------
__global__ __launch_bounds__(256)
void pnorm_kernel(f16* __restrict__ Pc, const float* __restrict__ pm,
                  const float* __restrict__ mcol, const float* __restrict__ rcol) {
  const int p = blockIdx.x, b = blockIdx.y;
  int itg = (int)((sqrtf(8.f * p + 1.f) - 1.f) * 0.5f);
  while ((itg + 1) * (itg + 2) / 2 <= p) ++itg;
  while (itg * (itg + 1) / 2 > p) --itg;
  const int jt = p - itg * (itg + 1) / 2;

  __shared__ float f[128];
  const int tid = threadIdx.x;
  if (tid < 128) {
    const int gj = jt * 128 + tid;
    f[tid] = __expf(pm[(itg * B_ + b) * T_ + gj] - mcol[b * T_ + gj]) * rcol[b * T_ + gj];
  }
  __syncthreads();

  f16* Pb = Pc + (size_t)b * T_ * T_ + (size_t)(itg * 128) * T_ + jt * 128;
  const int jl = (tid & 15) * 8, r0 = tid >> 4;
#pragma unroll
  for (int rr = 0; rr < 128; rr += 16) {
    f16x8 v = *(const f16x8*)&Pb[(size_t)(rr + r0) * T_ + jl];
    f16x8 o;
#pragma unroll
    for (int u = 0; u < 8; ++u) o[u] = (f16)((float)v[u] * f[jl + u]);
    *(f16x8*)&Pb[(size_t)(rr + r0) * T_ + jl] = o;
  }
}

// ---------------------------------------------------------------------------
extern "C" void kernel_launch(void* const* d_in, const int* in_sizes, int n_in,
                              void* d_out, int out_size, void* d_ws, size_t ws_size,
                              hipStream_t stream) {
  const float* X  = (const float*)d_in[0];
  const float* Wq = (const float*)d_in[1];
  const float* bq = (const float*)d_in[2];
  const float* Wk = (const float*)d_in[3];
  const float* bk = (const float*)d_in[4];
  const float* Wv = (const float*)d_in[5];
  const float* bv = (const float*)d_in[6];
  float* out = (float*)d_out;

  // Workspace carve (~210 MB)
  char* p = (char*)d_ws;
  auto carve = [&](size_t bytes) { char* r = p; p += (bytes + 255) & ~(size_t)255; return r; };
  f16*   Xh   = (f16*)carve((size_t)B_ * T_ * D_ * 2);
  f16*   Wqt  = (f16*)carve((size_t)D_ * KSZ * 2);
  f16*   Wkt  = (f16*)carve((size_t)D_ * KSZ * 2);
  f16*   Wvt  = (f16*)carve((size_t)D_ * D_ * 2);
  f16*   Qh   = (f16*)carve((size_t)B_ * T_ * KSZ * 2);
  f16*   Kh   = (f16*)carve((size_t)B_ * T_ * KSZ * 2);
  f16*   Vt   = (f16*)carve((size_t)B_ * D_ * T_ * 2);
  f16*   Pc   = (f16*)carve((size_t)B_ * T_ * T_ * 2);   // E, then P in place
  float* pm   = (float*)carve((size_t)NSLOT * B_ * T_ * 4);
  float* pd   = (float*)carve((size_t)NSLOT * B_ * T_ * 4);
  float* mcol = (float*)carve((size_t)B_ * T_ * 4);
  float* rcol = (float*)carve((size_t)B_ * T_ * 4);

  const dim3 blk(256);

  // Prep: casts + weight transposes; zero pd (skipped tiles never write it).
  hipMemsetAsync(pd, 0, (size_t)NSLOT * B_ * T_ * 4, stream);
  cast_f16_kernel<<<dim3((B_ * T_ * D_ / 4) / 256), blk, 0, stream>>>(X, Xh);
  transcast_kernel<<<dim3(32, 32), blk, 0, stream>>>(Wq, Wqt);
  transcast_kernel<<<dim3(32, 32), blk, 0, stream>>>(Wk, Wkt);
  transcast_kernel<<<dim3(32, 32), blk, 0, stream>>>(Wv, Wvt);

  // Projections (MFMA)
  gemm_nt<0><<<dim3(KSZ / 128, (B_ * T_) / 128, 1), blk, 0, stream>>>(Xh, Wqt, bq, Qh, nullptr, nullptr);
  gemm_nt<0><<<dim3(KSZ / 128, (B_ * T_) / 128, 1), blk, 0, stream>>>(Xh, Wkt, bk, Kh, nullptr, nullptr);
  gemm_nt<1><<<dim3(D_ / 128, (B_ * T_) / 128, 1), blk, 0, stream>>>(Xh, Wvt, bv, Vt, nullptr, nullptr);

  // Single fused QK pass: stats + E = exp(S - m_tile) into Pc
  qk_fused<<<dim3(NTRI, B_), blk, 0, stream>>>(Qh, Kh, pm, pd, Pc);
  colstats_combine<<<dim3(T_ / 256, B_), blk, 0, stream>>>(pm, pd, mcol, rcol);

  // Elementwise rescale E -> P (in place)
  pnorm_kernel<<<dim3(NTRI, B_), blk, 0, stream>>>(Pc, pm, mcol, rcol);

  // PV + residual: paired row-tiles (pr, 15-pr) -> uniform 17 K-tiles/block
  gemm_nt<3><<<dim3(D_ / 128, T_ / 256, B_), blk, 0, stream>>>(Pc, Vt, nullptr, nullptr, out, X);
}